// Round 2
// baseline (1332.236 us; speedup 1.0000x reference)
//
#include <hip/hip_runtime.h>
#include <hip/hip_bf16.h>
#include <stdint.h>

#define D_MODEL 1024
#define D_FF    4096
#define NEXP    8
#define NTOK    8192
#define NSLOT   16384

typedef __bf16 bf16x8 __attribute__((ext_vector_type(8)));
typedef float  f32x4  __attribute__((ext_vector_type(4)));
typedef unsigned short us8 __attribute__((ext_vector_type(8)));
typedef unsigned short us4 __attribute__((ext_vector_type(4)));

// ---- ws layout (bytes) ----
#define OFF_XB   0ull
#define OFF_WGT  16777216ull
#define OFF_WUT  83886080ull
#define OFF_WDT  150994944ull
#define OFF_H    218103808ull              // g then h in-place: 16384*4096*2
#define OFF_TOKE 352321536ull
#define OFF_TOKW 352387072ull
#define OFF_ROWT 352452608ull
#define OFF_WGTL 352518144ull
#define OFF_CNT  352583680ull
#define OFF_OFFS 352583744ull
#define OFF_FILL 352583808ull

__device__ __forceinline__ unsigned short f2b(float f) {
  union { float f; unsigned int u; } v; v.f = f;
  unsigned int r = (v.u + 0x7FFFu + ((v.u >> 16) & 1u)) >> 16;  // RNE
  return (unsigned short)r;
}
__device__ __forceinline__ float b2f(unsigned short b) {
  union { unsigned int u; float f; } v; v.u = ((unsigned int)b) << 16;
  return v.f;
}

__device__ __forceinline__ f32x4 MFMA(bf16x8 a, bf16x8 b, f32x4 c) {
  return __builtin_amdgcn_mfma_f32_16x16x32_bf16(a, b, c, 0, 0, 0);
}

__device__ __forceinline__ void GLL16(const void* g, void* l) {
  __builtin_amdgcn_global_load_lds(
      (__attribute__((address_space(1))) void*)g,
      (__attribute__((address_space(3))) void*)l, 16, 0, 0);
}

#define BAR()  asm volatile("s_barrier" ::: "memory")
#define VM8()  asm volatile("s_waitcnt vmcnt(8)" ::: "memory")
#define VM0()  asm volatile("s_waitcnt vmcnt(0)" ::: "memory")

// ---------------- x -> bf16 ----------------
__global__ __launch_bounds__(256) void k_cvt_x(const float* __restrict__ x,
                                               unsigned short* __restrict__ xb) {
  size_t i = ((size_t)blockIdx.x * 256 + threadIdx.x) * 8;
  float4 a = *(const float4*)(x + i);
  float4 b = *(const float4*)(x + i + 4);
  us8 o;
  o[0]=f2b(a.x); o[1]=f2b(a.y); o[2]=f2b(a.z); o[3]=f2b(a.w);
  o[4]=f2b(b.x); o[5]=f2b(b.y); o[6]=f2b(b.z); o[7]=f2b(b.w);
  *(us8*)(xb + i) = o;
}

// ------------- transpose+convert: in [E][R][C] f32 -> out [E][C][R] bf16 -------------
__global__ __launch_bounds__(256) void k_tc(const float* __restrict__ in,
                                            unsigned short* __restrict__ out,
                                            int R, int C) {
  __shared__ float t[64][65];
  int e = blockIdx.z;
  int r0 = blockIdx.y * 64, c0 = blockIdx.x * 64;
  const float* src = in + (size_t)e * R * C;
  unsigned short* dst = out + (size_t)e * R * C;
  int tid = threadIdx.x;
  int lr = tid >> 4;
  int lc = (tid & 15) * 4;
#pragma unroll
  for (int i = 0; i < 4; ++i) {
    float4 v = *(const float4*)(src + (size_t)(r0 + lr + 16 * i) * C + c0 + lc);
    t[lr + 16 * i][lc + 0] = v.x;
    t[lr + 16 * i][lc + 1] = v.y;
    t[lr + 16 * i][lc + 2] = v.z;
    t[lr + 16 * i][lc + 3] = v.w;
  }
  __syncthreads();
#pragma unroll
  for (int i = 0; i < 4; ++i) {
    int c = lr + 16 * i;
    us4 o;
    o[0] = f2b(t[lc + 0][c]);
    o[1] = f2b(t[lc + 1][c]);
    o[2] = f2b(t[lc + 2][c]);
    o[3] = f2b(t[lc + 3][c]);
    *(us4*)(dst + (size_t)(c0 + c) * R + r0 + lc) = o;
  }
}

// ---------------- router ----------------
__global__ __launch_bounds__(256) void k_router(const float* __restrict__ x,
                                                const float* __restrict__ rw,
                                                int* __restrict__ tok_e,
                                                float* __restrict__ tok_w,
                                                int* __restrict__ counts) {
  int w = threadIdx.x >> 6, l = threadIdx.x & 63;
  int t = blockIdx.x * 4 + w;
  const float* xr = x + (size_t)t * D_MODEL + l * 16;
  float4 xa = *(const float4*)(xr);
  float4 xb4 = *(const float4*)(xr + 4);
  float4 xc = *(const float4*)(xr + 8);
  float4 xd = *(const float4*)(xr + 12);
  float lg[NEXP];
#pragma unroll
  for (int e = 0; e < NEXP; ++e) {
    const float* wr = rw + e * D_MODEL + l * 16;
    float4 wa = *(const float4*)(wr);
    float4 wb = *(const float4*)(wr + 4);
    float4 wc = *(const float4*)(wr + 8);
    float4 wd4 = *(const float4*)(wr + 12);
    float s = xa.x*wa.x + xa.y*wa.y + xa.z*wa.z + xa.w*wa.w
            + xb4.x*wb.x + xb4.y*wb.y + xb4.z*wb.z + xb4.w*wb.w
            + xc.x*wc.x + xc.y*wc.y + xc.z*wc.z + xc.w*wc.w
            + xd.x*wd4.x + xd.y*wd4.y + xd.z*wd4.z + xd.w*wd4.w;
#pragma unroll
    for (int o = 32; o; o >>= 1) s += __shfl_xor(s, o, 64);
    lg[e] = s;
  }
  if (l == 0) {
    int e1 = 0; float l1 = lg[0];
#pragma unroll
    for (int e = 1; e < NEXP; ++e) if (lg[e] > l1) { l1 = lg[e]; e1 = e; }
    int e2 = -1; float l2 = -3.4e38f;
#pragma unroll
    for (int e = 0; e < NEXP; ++e) if (e != e1 && lg[e] > l2) { l2 = lg[e]; e2 = e; }
    float w1 = 1.f / (1.f + expf(l2 - l1));
    tok_e[2 * t] = e1; tok_e[2 * t + 1] = e2;
    tok_w[2 * t] = w1; tok_w[2 * t + 1] = 1.f - w1;
    atomicAdd(&counts[e1], 1);
    atomicAdd(&counts[e2], 1);
  }
}

__global__ void k_scan(const int* __restrict__ counts, int* __restrict__ offs) {
  if (threadIdx.x == 0) {
    int s = 0;
#pragma unroll
    for (int e = 0; e < NEXP; ++e) { offs[e] = s; s += counts[e]; }
    offs[NEXP] = s;
  }
}

__global__ __launch_bounds__(256) void k_scatter(const int* __restrict__ tok_e,
                                                 const float* __restrict__ tok_w,
                                                 const int* __restrict__ offs,
                                                 int* __restrict__ fill,
                                                 int* __restrict__ rowtok,
                                                 float* __restrict__ wgtl) {
  int t = blockIdx.x * 256 + threadIdx.x;
#pragma unroll
  for (int k = 0; k < 2; ++k) {
    int e = tok_e[2 * t + k];
    int p = atomicAdd(&fill[e], 1);
    int s = offs[e] + p;
    rowtok[s] = t;
    wgtl[s] = tok_w[2 * t + k];
  }
}

// ================= 8-phase 256x256xBK64 pipelined GEMM =================
// MODE 0: g = A@B^T           (A = xb gathered via rowtok, B = wgT)  -> hbuf bf16
// MODE 1: h = silu(g)*(A@B^T) (B = wuT; g read from hbuf, h in place)
// MODE 2: out += w * (A@B^T)  (A = hbuf direct, B = wdT, atomic scatter)
template<int MODE, int KDIM, int NB>
__global__ __launch_bounds__(512, 2) void gemm8(
    const unsigned short* __restrict__ Ag,
    const unsigned short* __restrict__ Bg,
    const int* __restrict__ rowtok,
    const float* __restrict__ wgtl,
    const int* __restrict__ offs,
    unsigned short* __restrict__ hbuf,
    float* __restrict__ out) {
  constexpr int NKT = KDIM / 64;
  int e = blockIdx.z;
  int eoff = offs[e];
  int cnt = offs[e + 1] - eoff;
  int m0 = blockIdx.y * 256;
  if (m0 >= cnt) return;
  int n0 = blockIdx.x * 256;

  __shared__ __align__(16) unsigned short lds[65536];  // 128 KiB, 2 x (A 32K + B 32K)
  char* ldsb = (char*)lds;

  int tid = threadIdx.x;
  int l = tid & 63, w = tid >> 6;
  int wm = w >> 2, wn = w & 3;

  // ---- staging source pointers (swizzled source slot; LDS dest linear) ----
  int srow = tid >> 3;                    // 0..63
  int sslot = (tid & 7) ^ (srow & 7);     // T2 inverse-swizzle on source
  const unsigned short* aB[4];
  const unsigned short* bB[4];
  const unsigned short* Bexp = Bg + (size_t)e * (size_t)NB * KDIM;
#pragma unroll
  for (int h = 0; h < 2; ++h)
#pragma unroll
    for (int j = 0; j < 2; ++j) {
      int r = m0 + h * 128 + j * 64 + srow;
      int rc = r < cnt ? r : cnt - 1;
      if (MODE < 2)
        aB[h * 2 + j] = Ag + (size_t)rowtok[eoff + rc] * D_MODEL + sslot * 8;
      else
        aB[h * 2 + j] = Ag + (size_t)(eoff + rc) * D_FF + sslot * 8;
      bB[h * 2 + j] = Bexp + (size_t)(n0 + h * 128 + j * 64 + srow) * KDIM + sslot * 8;
    }

#define STAGE_A(t, buf) {                                                  \
    int k0 = (t) * 64;                                                     \
    GLL16(aB[0] + k0, ldsb + (buf) * 65536 + 0 * 8192 + tid * 16);         \
    GLL16(aB[1] + k0, ldsb + (buf) * 65536 + 1 * 8192 + tid * 16);         \
    GLL16(aB[2] + k0, ldsb + (buf) * 65536 + 2 * 8192 + tid * 16);         \
    GLL16(aB[3] + k0, ldsb + (buf) * 65536 + 3 * 8192 + tid * 16); }
#define STAGE_B(t, buf) {                                                  \
    int k0 = (t) * 64;                                                     \
    GLL16(bB[0] + k0, ldsb + (buf) * 65536 + 32768 + 0 * 8192 + tid * 16); \
    GLL16(bB[1] + k0, ldsb + (buf) * 65536 + 32768 + 1 * 8192 + tid * 16); \
    GLL16(bB[2] + k0, ldsb + (buf) * 65536 + 32768 + 2 * 8192 + tid * 16); \
    GLL16(bB[3] + k0, ldsb + (buf) * 65536 + 32768 + 3 * 8192 + tid * 16); }

  // ds_read address helpers (swizzled 16B slot within 128B row)
#define RDA(L, mi, kk) (*(const bf16x8*)((L) +                             \
    (wm * 128 + (mi) * 16 + (l & 15)) * 128 +                              \
    ((((l >> 4) + 4 * (kk)) ^ (l & 7)) * 16)))
#define RDB(L, ni, kk) (*(const bf16x8*)((L) + 32768 +                     \
    (wn * 64 + (ni) * 16 + (l & 15)) * 128 +                               \
    ((((l >> 4) + 4 * (kk)) ^ (l & 7)) * 16)))

  f32x4 acc[8][4];
#pragma unroll
  for (int i = 0; i < 8; ++i)
#pragma unroll
    for (int j = 0; j < 4; ++j) acc[i][j] = (f32x4){0.f, 0.f, 0.f, 0.f};

  // prologue: tile0 -> buf0, tile1 -> buf1; drain tile0, keep tile1 in flight
  STAGE_A(0, 0); STAGE_B(0, 0);
  STAGE_A(1, 1); STAGE_B(1, 1);
  VM8();
  BAR();

  for (int t = 0; t < NKT; ++t) {
    int cur = t & 1;
    char* L = ldsb + cur * 65536;
    bf16x8 aF[4][2], aF2[4][2], bF[2][2], bF2[2][2];

    // ---- phase 0: 12 ds_reads; MFMA quad (mi0-3 x ni0-1) ----
#pragma unroll
    for (int mi = 0; mi < 4; ++mi)
#pragma unroll
      for (int kk = 0; kk < 2; ++kk) aF[mi][kk] = RDA(L, mi, kk);
#pragma unroll
    for (int ni = 0; ni < 2; ++ni)
#pragma unroll
      for (int kk = 0; kk < 2; ++kk) bF[ni][kk] = RDB(L, ni, kk);
    BAR();
    __builtin_amdgcn_s_setprio(1);
#pragma unroll
    for (int mi = 0; mi < 4; ++mi)
#pragma unroll
      for (int ni = 0; ni < 2; ++ni)
#pragma unroll
        for (int kk = 0; kk < 2; ++kk)
          acc[mi][ni] = MFMA(aF[mi][kk], bF[ni][kk], acc[mi][ni]);
    __builtin_amdgcn_s_setprio(0);
    BAR();

    // ---- phase 1: 4 ds_reads; MFMA quad (mi0-3 x ni2-3) ----
#pragma unroll
    for (int ni = 0; ni < 2; ++ni)
#pragma unroll
      for (int kk = 0; kk < 2; ++kk) bF2[ni][kk] = RDB(L, ni + 2, kk);
    BAR();
    __builtin_amdgcn_s_setprio(1);
#pragma unroll
    for (int mi = 0; mi < 4; ++mi)
#pragma unroll
      for (int ni = 0; ni < 2; ++ni)
#pragma unroll
        for (int kk = 0; kk < 2; ++kk)
          acc[mi][ni + 2] = MFMA(aF[mi][kk], bF2[ni][kk], acc[mi][ni + 2]);
    __builtin_amdgcn_s_setprio(0);
    BAR();

    // ---- phase 2: 8 ds_reads; stage B(t+2) into cur (B region dead); MFMA (mi4-7 x ni0-1) ----
#pragma unroll
    for (int mi = 0; mi < 4; ++mi)
#pragma unroll
      for (int kk = 0; kk < 2; ++kk) aF2[mi][kk] = RDA(L, mi + 4, kk);
    if (t + 2 < NKT) STAGE_B(t + 2, cur);
    BAR();
    __builtin_amdgcn_s_setprio(1);
#pragma unroll
    for (int mi = 0; mi < 4; ++mi)
#pragma unroll
      for (int ni = 0; ni < 2; ++ni)
#pragma unroll
        for (int kk = 0; kk < 2; ++kk)
          acc[mi + 4][ni] = MFMA(aF2[mi][kk], bF[ni][kk], acc[mi + 4][ni]);
    __builtin_amdgcn_s_setprio(0);
    BAR();

    // ---- phase 3: stage A(t+2) (A region dead); MFMA (mi4-7 x ni2-3); counted vmcnt ----
    if (t + 2 < NKT) STAGE_A(t + 2, cur);
    BAR();
    __builtin_amdgcn_s_setprio(1);
#pragma unroll
    for (int mi = 0; mi < 4; ++mi)
#pragma unroll
      for (int ni = 0; ni < 2; ++ni)
#pragma unroll
        for (int kk = 0; kk < 2; ++kk)
          acc[mi + 4][ni + 2] = MFMA(aF2[mi][kk], bF2[ni][kk], acc[mi + 4][ni + 2]);
    __builtin_amdgcn_s_setprio(0);
    if (t + 2 < NKT) { VM8(); } else { VM0(); }  // last tiles: must fully drain
    BAR();
  }

  // ---- epilogue ----
#pragma unroll
  for (int mi = 0; mi < 8; ++mi) {
#pragma unroll
    for (int j = 0; j < 4; ++j) {
      int row = wm * 128 + mi * 16 + (l >> 4) * 4 + j;
      if (m0 + row < cnt) {
        int grow = eoff + m0 + row;
        if (MODE == 0) {
          size_t base = (size_t)grow * D_FF + n0;
#pragma unroll
          for (int ni = 0; ni < 4; ++ni) {
            int col = wn * 64 + ni * 16 + (l & 15);
            hbuf[base + col] = f2b(acc[mi][ni][j]);
          }
        } else if (MODE == 1) {
          size_t base = (size_t)grow * D_FF + n0;
#pragma unroll
          for (int ni = 0; ni < 4; ++ni) {
            int col = wn * 64 + ni * 16 + (l & 15);
            float g = b2f(hbuf[base + col]);
            float s = g / (1.f + __expf(-g)) * acc[mi][ni][j];
            hbuf[base + col] = f2b(s);
          }
        } else {
          float wv = wgtl[grow];
          int tok = rowtok[grow];
          float* ob = out + (size_t)tok * D_MODEL + n0;
#pragma unroll
          for (int ni = 0; ni < 4; ++ni) {
            int col = wn * 64 + ni * 16 + (l & 15);
            atomicAdd(ob + col, acc[mi][ni][j] * wv);
          }
        }
      }
    }
  }
#undef STAGE_A
#undef STAGE_B
#undef RDA
#undef RDB
}

extern "C" void kernel_launch(void* const* d_in, const int* in_sizes, int n_in,
                              void* d_out, int out_size, void* d_ws, size_t ws_size,
                              hipStream_t stream) {
  const float* x  = (const float*)d_in[0];
  const float* rw = (const float*)d_in[1];
  const float* wg = (const float*)d_in[2];
  const float* wu = (const float*)d_in[3];
  const float* wd = (const float*)d_in[4];
  float* out = (float*)d_out;
  char* ws = (char*)d_ws;

  unsigned short* xb  = (unsigned short*)(ws + OFF_XB);
  unsigned short* wgT = (unsigned short*)(ws + OFF_WGT);
  unsigned short* wuT = (unsigned short*)(ws + OFF_WUT);
  unsigned short* wdT = (unsigned short*)(ws + OFF_WDT);
  unsigned short* hb  = (unsigned short*)(ws + OFF_H);
  int*   tok_e  = (int*)(ws + OFF_TOKE);
  float* tok_w  = (float*)(ws + OFF_TOKW);
  int*   rowtok = (int*)(ws + OFF_ROWT);
  float* wgtl   = (float*)(ws + OFF_WGTL);
  int*   counts = (int*)(ws + OFF_CNT);
  int*   offs   = (int*)(ws + OFF_OFFS);
  int*   fill   = (int*)(ws + OFF_FILL);

  hipMemsetAsync(out, 0, (size_t)NTOK * D_MODEL * 4, stream);
  hipMemsetAsync(ws + OFF_CNT, 0, 192, stream);

  k_cvt_x<<<4096, 256, 0, stream>>>(x, xb);
  k_tc<<<dim3(64, 16, 8), 256, 0, stream>>>(wg, wgT, D_MODEL, D_FF);
  k_tc<<<dim3(64, 16, 8), 256, 0, stream>>>(wu, wuT, D_MODEL, D_FF);
  k_tc<<<dim3(16, 64, 8), 256, 0, stream>>>(wd, wdT, D_FF, D_MODEL);

  k_router<<<NTOK / 4, 256, 0, stream>>>(x, rw, tok_e, tok_w, counts);
  k_scan<<<1, 64, 0, stream>>>(counts, offs);
  k_scatter<<<NTOK / 256, 256, 0, stream>>>(tok_e, tok_w, offs, fill, rowtok, wgtl);

  // G-pass -> g in hb; U-pass -> h in place; D-pass -> atomic combine into out
  gemm8<0, D_MODEL, D_FF><<<dim3(16, 32, 8), 512, 0, stream>>>(xb, wgT, rowtok, wgtl, offs, hb, out);
  gemm8<1, D_MODEL, D_FF><<<dim3(16, 32, 8), 512, 0, stream>>>(xb, wuT, rowtok, wgtl, offs, hb, out);
  gemm8<2, D_FF, D_MODEL><<<dim3(4, 32, 8), 512, 0, stream>>>(hb, wdT, rowtok, wgtl, offs, hb, out);
}